// Round 14
// baseline (113.651 us; speedup 1.0000x reference)
//
#include <hip/hip_runtime.h>
#include <math.h>

#define B_    8
#define Q_    900
#define NCLS_ 11
#define NANC_ 100
#define H_    200
#define W_    200
#define C_    256
#define HHALF 100
#define CHNK_ 113           // rank chunk per block in topk
#define CHEV_ 16            // events per staged chunk (16 KB per buffer)
#define EVSTR_ 224          // per-row event stride in ws (ints); ne <= 200

typedef float f32x4_ __attribute__((ext_vector_type(4)));

// ---------------------------------------------------------------------------
// Kernel 1: scores + rank + box transform (R12, proven).
// ---------------------------------------------------------------------------
__global__ __launch_bounds__(128) void segdet_topk_kernel(
    const float* __restrict__ pred_boxes,
    const float* __restrict__ pred_logits,
    const float* __restrict__ view,
    int*  __restrict__ ws_idx,
    int4* __restrict__ ws_box)
{
    const int b     = blockIdx.x >> 3;
    const int chunk = blockIdx.x & 7;
    const int tid   = threadIdx.x;

    __shared__ __align__(16) float sc[Q_];

    for (int q2 = tid; q2 < Q_; q2 += 128) {
        const float* l = pred_logits + (b * Q_ + q2) * NCLS_;
        float v[NCLS_];
        float m = -INFINITY;
        #pragma unroll
        for (int i = 0; i < NCLS_; ++i) { v[i] = l[i]; m = fmaxf(m, v[i]); }
        float s = 0.0f, e10 = -INFINITY;
        #pragma unroll
        for (int i = 0; i < NCLS_; ++i) {
            float e = expf(v[i] - m);
            s += e;
            if (i < NCLS_ - 1) e10 = fmaxf(e10, e);
        }
        sc[q2] = e10 / s;
    }
    __syncthreads();

    const int q = chunk * CHNK_ + tid;
    if (tid < CHNK_ && q < Q_) {
        const float my = sc[q];
        int rank = 0;
        #pragma unroll 4
        for (int j4 = 0; j4 < Q_ / 4; ++j4) {
            const float4 o = *(const float4*)&sc[j4 * 4];
            const int j = j4 * 4;
            rank += (o.x > my) || (o.x == my && (j + 0) < q);
            rank += (o.y > my) || (o.y == my && (j + 1) < q);
            rank += (o.z > my) || (o.z == my && (j + 2) < q);
            rank += (o.w > my) || (o.w == my && (j + 3) < q);
        }
        if (rank < NANC_) {
            const float* bx = pred_boxes + (b * Q_ + q) * 4;
            double cx = (double)bx[0], cy = (double)bx[1];
            double w  = exp((double)bx[2]);
            double h  = exp((double)bx[3]);
            double p[5] = { cx - 0.5 * w, cy - 0.5 * h,
                            cx + 0.5 * w, cy + 0.5 * h, 1.0 };
            const float* v5 = view + b * 25;
            int ico[4];
            #pragma unroll
            for (int i = 0; i < 4; ++i) {
                double acc = 0.0;
                #pragma unroll
                for (int j = 0; j < 5; ++j) acc += (double)v5[i * 5 + j] * p[j];
                ico[i] = (int)acc;
            }
            int x0 = min(max(ico[0], 0), W_);
            int y0 = min(max(ico[1], 0), H_);
            int x1 = min(max(ico[2], 0), W_);
            int y1 = min(max(ico[3], 0), H_);
            const int slot = b * NANC_ + rank;
            ws_idx[slot] = q;
            ws_box[slot] = make_int4(x0, y0, x1, y1);
        }
    }
}

__device__ __forceinline__ void nt_store4(float* p, f32x4_ v) {
    __builtin_nontemporal_store(v, (f32x4_*)p);
}

__device__ __forceinline__ void gload_lds_16(const float* g, float* l) {
    __builtin_amdgcn_global_load_lds(
        (const __attribute__((address_space(1))) void*)g,
        (__attribute__((address_space(3))) void*)l,
        16, 0, 0);
}

// ---------------------------------------------------------------------------
// Kernel 2 (row-prep): per-(b,h)-row sorted event list + mask, 4 rows/block.
// b128 box reads (count/scatter loops 4x fewer iters), per-pixel scatter
// (each thread writes its own pixel's entries in k-order -> NO O(tid^2) loop,
// identical event order to R4-R13), 2 barriers. Writes:
//   g_hdr[rid] = ne;  g_ev[rid*EVSTR_ + e] = q | pix<<10 | (close?1<<31)
//   mask row (so the store kernel never touches mask).
// ---------------------------------------------------------------------------
__global__ __launch_bounds__(1024) void segdet_prep_kernel(
    const int*  __restrict__ ws_idx,
    const int4* __restrict__ ws_box,
    int*  __restrict__ g_hdr,
    int*  __restrict__ g_ev,
    float* __restrict__ mask)
{
    const int sub = threadIdx.x >> 8;          // row-group 0..3
    const int t   = threadIdx.x & 255;         // thread within group
    const int ln  = threadIdx.x & 63;
    const int wv2 = (threadIdx.x >> 6) & 3;    // wave within group
    const int rid = blockIdx.x * 4 + sub;      // 0..1599
    const int b   = rid / H_;
    const int h   = rid % H_;

    __shared__ __align__(16) int s_box[4][104]; // packed x0|x1<<8|q<<16, padded
    __shared__ int s_na[4];
    __shared__ int s_ws[4][4];

    // ---- per-group wave-0 ballot compaction (deterministic k-order)
    if (wv2 == 0) {
        int na = 0;
        #pragma unroll
        for (int it = 0; it < 2; ++it) {
            int k = it * 64 + ln;
            bool act = false; int packed = 0;
            if (k < NANC_) {
                int4 bx = ws_box[b * NANC_ + k];
                int qi  = ws_idx[b * NANC_ + k];
                act = (bx.y <= h) && (h < bx.w) && (bx.x < bx.z);
                packed = bx.x | (bx.z << 8) | (qi << 16);
            }
            unsigned long long ball = __ballot(act);
            int pos = na + (int)__popcll(ball & ((1ull << ln) - 1ull));
            if (act) s_box[sub][pos] = packed;
            na += (int)__popcll(ball);
        }
        for (int idx = na + ln; idx < 104; idx += 64)
            s_box[sub][idx] = 0xFFFF;          // pad: x0=255,x1=255 (never match)
        if (ln == 0) s_na[sub] = na;
    }
    __syncthreads();                           // B1

    const int nact = s_na[sub];
    const int nk4  = (nact + 3) >> 2;

    // ---- per-pixel open/close counts + coverage (b128 reads, pad-safe)
    int nopen = 0, ncl = 0, cov = 0;
#define CNT1_(PK) { const int x0_ = (PK) & 0xFF, x1_ = ((PK) >> 8) & 0xFF;    \
        nopen += (x0_ == t); ncl += (x1_ == t);                               \
        cov   += (x0_ <= t) && (t < x1_); }
    if (t < W_) {
        for (int k4 = 0; k4 < nk4; ++k4) {
            const int4 p4 = *(const int4*)&s_box[sub][k4 * 4];
            CNT1_(p4.x); CNT1_(p4.y); CNT1_(p4.z); CNT1_(p4.w);
        }
        mask[(size_t)rid * W_ + t] = (cov > 0) ? 1.0f : 0.0f;
    }
#undef CNT1_
    const int ntot = nopen + ncl;

    // ---- shuffle scan (per wave) + cross-wave combine within group
    int incl = ntot;
    #pragma unroll
    for (int d = 1; d < 64; d <<= 1) {
        int u = __shfl_up(incl, d);
        incl = (ln >= d) ? incl + u : incl;
    }
    if (ln == 63) s_ws[sub][wv2] = incl;
    __syncthreads();                           // B2

    int prev = 0;
    #pragma unroll
    for (int j = 0; j < 4; ++j) prev += (j < wv2) ? s_ws[sub][j] : 0;
    const int ne  = s_ws[sub][0] + s_ws[sub][1] + s_ws[sub][2] + s_ws[sub][3];
    const int ofs = prev + incl - ntot;        // exclusive scan (this pixel)
    if (t == 0) g_hdr[rid] = ne;

    // ---- per-pixel scatter: opens (k-order) then closes (k-order)
    if (t < W_ && ntot > 0) {
        int po = ofs, pc = ofs + nopen;
        int* dst = g_ev + (size_t)rid * EVSTR_;
#define SCT1_(PK) { const int x0_ = (PK) & 0xFF, x1_ = ((PK) >> 8) & 0xFF;    \
        const int q_ = (PK) >> 16;                                            \
        if (x0_ == t) dst[po++] = q_ | (t << 10);                             \
        if (x1_ == t) dst[pc++] = (int)((unsigned)q_ | ((unsigned)t << 10)    \
                                         | 0x80000000u); }
        for (int k4 = 0; k4 < nk4; ++k4) {
            const int4 p4 = *(const int4*)&s_box[sub][k4 * 4];
            SCT1_(p4.x); SCT1_(p4.y); SCT1_(p4.z); SCT1_(p4.w);
        }
#undef SCT1_
    }
}

// ---------------------------------------------------------------------------
// Kernel 3 (store-stream): preamble = 1 header read + 1 coalesced 224-int
// event-list load; then R13's chunk-staged walk (async global_load_lds into
// 2x16KB LDS dbuf; feature reads on lgkmcnt; stores never drained mid-walk).
// Mask untouched (K2 wrote it). Center-out row order packs the tail.
// ---------------------------------------------------------------------------
__global__ __launch_bounds__(256) void segdet_bev2_kernel(
    const float* __restrict__ box_feats,
    const int*   __restrict__ g_hdr,
    const int*   __restrict__ g_ev,
    float* __restrict__ bev)
{
    const int hidx = blockIdx.x / B_;
    const int b    = blockIdx.x % B_;
    const int h    = (hidx & 1) ? (HHALF - 1 - (hidx >> 1)) : (HHALF + (hidx >> 1));
    const int rid  = b * H_ + h;

    const int tid = threadIdx.x;
    const int ln  = tid & 63;
    const int wv  = tid >> 6;

    __shared__ __align__(16) float s_chunk[2][CHEV_ * C_];  // 32 KB
    __shared__ int s_e[EVSTR_];

    const int ne = g_hdr[rid];                 // uniform broadcast load
    float* obase = bev + (size_t)rid * W_ * C_ + ln * 4;

    if (ne == 0) {                             // empty row: pure zero stream
        const f32x4_ z = {0.f, 0.f, 0.f, 0.f};
        for (int w = wv; w < W_; w += 4)
            nt_store4(obase + (size_t)w * C_, z);
        return;
    }

    if (tid < EVSTR_) s_e[tid] = g_ev[(size_t)rid * EVSTR_ + tid];
    __syncthreads();                           // entries visible

    const float* fbase = box_feats + (size_t)b * Q_ * C_ + ln * 4;
    const int nchunk = (ne + CHEV_ - 1) / CHEV_;

#define STAGE_(CI)                                                            \
    {                                                                         \
        const int base_ = (CI) * CHEV_;                                       \
        float* dst_ = &s_chunk[(CI) & 1][0];                                  \
        _Pragma("unroll")                                                     \
        for (int j = 0; j < 4; ++j) {                                         \
            const int e_ = base_ + wv * 4 + j;                                \
            if (e_ < ne) {                                                    \
                const int q_ = s_e[e_] & 0x3FF;                               \
                gload_lds_16(fbase + (size_t)q_ * C_,                         \
                             dst_ + (wv * 4 + j) * C_);                       \
            }                                                                 \
        }                                                                     \
    }

    STAGE_(0);
    __syncthreads();                           // chunk 0 staged

    f32x4_ acc = {0.f, 0.f, 0.f, 0.f};
    int cnt = 0;
    int w = wv;
    for (int ci = 0; ci < nchunk; ++ci) {
        if (ci + 1 < nchunk) STAGE_(ci + 1);   // overlaps walk of chunk ci
        const int ebeg = ci * CHEV_;
        const int eend = (ne < ebeg + CHEV_) ? ne : (ebeg + CHEV_);
        const float* cb = &s_chunk[ci & 1][0];
        for (int e = ebeg; e < eend; ++e) {
            const int ent = s_e[e];
            const int pe  = (ent >> 10) & 0xFF;
            for (; w < pe; w += 4)
                nt_store4(obase + (size_t)w * C_, acc);
            const f32x4_ f = *(const f32x4_*)&cb[(e - ebeg) * C_ + ln * 4];
            if (ent < 0) { acc -= f; --cnt; }
            else         { acc += f; ++cnt; }
            if (cnt == 0) acc = (f32x4_){0.f, 0.f, 0.f, 0.f};
        }
        __syncthreads();                       // next chunk staged; buffer free
    }
#undef STAGE_
    for (; w < W_; w += 4)
        nt_store4(obase + (size_t)w * C_, acc);
}

// ---------------------------------------------------------------------------
// Fallback bev kernel (R13, proven 101us) — used only if ws_size is too small
// for the event-list scratch.
// ---------------------------------------------------------------------------
__global__ __launch_bounds__(256) void segdet_bev_kernel(
    const float* __restrict__ box_feats,
    const int*   __restrict__ ws_idx,
    const int4*  __restrict__ ws_box,
    float* __restrict__ bev,
    float* __restrict__ mask)
{
    const int hidx = blockIdx.x / B_;
    const int b    = blockIdx.x % B_;
    const int h    = (hidx & 1) ? (HHALF - 1 - (hidx >> 1)) : (HHALF + (hidx >> 1));

    const int tid = threadIdx.x;
    const int ln  = tid & 63;
    const int wv  = tid >> 6;

    __shared__ __align__(16) float s_chunk[2][CHEV_ * C_];
    __shared__ int s_box[NANC_];
    __shared__ int s_nact;
    __shared__ int s_nopen[W_];
    __shared__ int s_ofs[W_ + 1];
    __shared__ int s_ent[2 * NANC_];
    __shared__ int s_wsum[4];

    if (tid < 64) {
        int na = 0;
        #pragma unroll
        for (int it = 0; it < 2; ++it) {
            int k = it * 64 + ln;
            bool act = false;
            int packed = 0;
            if (k < NANC_) {
                int4 bx = ws_box[b * NANC_ + k];
                int qi  = ws_idx[b * NANC_ + k];
                act = (bx.y <= h) && (h < bx.w) && (bx.x < bx.z);
                packed = bx.x | (bx.z << 8) | (qi << 16);
            }
            unsigned long long ball = __ballot(act);
            int pos = na + (int)__popcll(ball & ((1ull << ln) - 1ull));
            if (act) s_box[pos] = packed;
            na += (int)__popcll(ball);
        }
        if (ln == 0) s_nact = na;
    }
    __syncthreads();

    const int nact = s_nact;
    float* obase = bev + (size_t)(b * H_ + h) * W_ * C_ + ln * 4;
    float* mrow  = mask + (size_t)(b * H_ + h) * W_;

    if (nact == 0) {
        const f32x4_ z = {0.f, 0.f, 0.f, 0.f};
        for (int w = wv; w < W_; w += 4)
            nt_store4(obase + (size_t)w * C_, z);
        if (tid < W_) __builtin_nontemporal_store(0.0f, &mrow[tid]);
        return;
    }

    int ntot = 0;
    if (tid < W_) {
        int nopen = 0, nclose = 0, cov = 0;
        for (int k = 0; k < nact; ++k) {
            int pk = s_box[k];
            int x0 = pk & 0xFF, x1 = (pk >> 8) & 0xFF;
            nopen  += (x0 == tid);
            nclose += (x1 == tid);
            cov    += (x0 <= tid) && (tid < x1);
        }
        s_nopen[tid] = nopen;
        ntot = nopen + nclose;
        __builtin_nontemporal_store((cov > 0) ? 1.0f : 0.0f, &mrow[tid]);
    }

    int incl = ntot;
    #pragma unroll
    for (int d = 1; d < 64; d <<= 1) {
        int u = __shfl_up(incl, d);
        incl = (ln >= d) ? incl + u : incl;
    }
    if (ln == 63) s_wsum[wv] = incl;
    __syncthreads();

    int prev = 0;
    #pragma unroll
    for (int j = 0; j < 4; ++j) prev += (j < wv) ? s_wsum[j] : 0;
    const int ne = s_wsum[0] + s_wsum[1] + s_wsum[2] + s_wsum[3];
    if (tid < W_) s_ofs[tid] = prev + incl - ntot;
    if (tid == 0) s_ofs[W_] = ne;
    __syncthreads();

    if (tid < nact) {
        int pk = s_box[tid];
        int x0 = pk & 0xFF, x1 = (pk >> 8) & 0xFF, q = pk >> 16;
        int ro = 0, rc = 0;
        for (int j = 0; j < tid; ++j) {
            int pj = s_box[j];
            ro += ((pj & 0xFF) == x0);
            rc += (((pj >> 8) & 0xFF) == x1);
        }
        s_ent[s_ofs[x0] + ro] = q | (x0 << 10);
        if (x1 < W_)
            s_ent[s_ofs[x1] + s_nopen[x1] + rc] =
                (int)((unsigned)q | ((unsigned)x1 << 10) | 0x80000000u);
    }
    __syncthreads();

    const float* fbase = box_feats + (size_t)b * Q_ * C_ + ln * 4;
    const int nchunk = (ne + CHEV_ - 1) / CHEV_;

#define STAGE_(CI)                                                            \
    {                                                                         \
        const int base_ = (CI) * CHEV_;                                       \
        float* dst_ = &s_chunk[(CI) & 1][0];                                  \
        _Pragma("unroll")                                                     \
        for (int j = 0; j < 4; ++j) {                                         \
            const int e_ = base_ + wv * 4 + j;                                \
            if (e_ < ne) {                                                    \
                const int q_ = s_ent[e_] & 0x3FF;                             \
                gload_lds_16(fbase + (size_t)q_ * C_,                         \
                             dst_ + (wv * 4 + j) * C_);                       \
            }                                                                 \
        }                                                                     \
    }

    STAGE_(0);
    __syncthreads();

    f32x4_ acc = {0.f, 0.f, 0.f, 0.f};
    int cnt = 0;
    int w = wv;
    for (int ci = 0; ci < nchunk; ++ci) {
        if (ci + 1 < nchunk) STAGE_(ci + 1);
        const int ebeg = ci * CHEV_;
        const int eend = (ne < ebeg + CHEV_) ? ne : (ebeg + CHEV_);
        const float* cb = &s_chunk[ci & 1][0];
        for (int e = ebeg; e < eend; ++e) {
            const int ent = s_ent[e];
            const int pe  = (ent >> 10) & 0xFF;
            for (; w < pe; w += 4)
                nt_store4(obase + (size_t)w * C_, acc);
            const f32x4_ f = *(const f32x4_*)&cb[(e - ebeg) * C_ + ln * 4];
            if (ent < 0) { acc -= f; --cnt; }
            else         { acc += f; ++cnt; }
            if (cnt == 0) acc = (f32x4_){0.f, 0.f, 0.f, 0.f};
        }
        __syncthreads();
    }
#undef STAGE_
    for (; w < W_; w += 4)
        nt_store4(obase + (size_t)w * C_, acc);
}

// ---------------------------------------------------------------------------
extern "C" void kernel_launch(void* const* d_in, const int* in_sizes, int n_in,
                              void* d_out, int out_size, void* d_ws, size_t ws_size,
                              hipStream_t stream) {
    const float* pred_boxes  = (const float*)d_in[0];
    const float* pred_logits = (const float*)d_in[1];
    const float* box_feats   = (const float*)d_in[2];
    const float* view        = (const float*)d_in[3];

    float* bev  = (float*)d_out;
    float* mask = bev + (size_t)B_ * H_ * W_ * C_;

    int*  ws_idx = (int*)d_ws;                             // @0      (3200 B)
    int4* ws_box = (int4*)((char*)d_ws + 3200);            // @3200   (12800 B)
    int*  g_hdr  = (int*)((char*)d_ws + 16000);            // @16000  (6400 B)
    int*  g_ev   = (int*)((char*)d_ws + 22400);            // @22400  (1433600 B)
    const size_t need = 22400ull + (size_t)B_ * H_ * EVSTR_ * 4ull;  // 1456000

    segdet_topk_kernel<<<B_ * 8, 128, 0, stream>>>(pred_boxes, pred_logits, view,
                                                   ws_idx, ws_box);
    if (ws_size >= need) {
        segdet_prep_kernel<<<(B_ * H_) / 4, 1024, 0, stream>>>(
            ws_idx, ws_box, g_hdr, g_ev, mask);
        segdet_bev2_kernel<<<B_ * H_, 256, 0, stream>>>(
            box_feats, g_hdr, g_ev, bev);
    } else {
        segdet_bev_kernel<<<B_ * H_, 256, 0, stream>>>(
            box_feats, ws_idx, ws_box, bev, mask);
    }
}